// Round 2
// baseline (510.842 us; speedup 1.0000x reference)
//
#include <hip/hip_runtime.h>
#include <cstdint>
#include <cstddef>

#define NN 500000            // nodes
#define NC ((NN + 63) / 64)  // 7813 chunks of 64 nodes
#define NB 768               // blocks (3 per CU by LDS)
// IN_CH=64, HEADS=4, OUT_CH=32, F=128 out feats, GH=256 gate hidden, SEGS=1024

typedef __attribute__((ext_vector_type(8))) short short8;   // 8 bf16 (4 VGPRs) MFMA frag
typedef __attribute__((ext_vector_type(4))) float floatx4;  // MFMA accumulator

__device__ __forceinline__ unsigned short f2bf(float f) {
  union { float f; unsigned u; } v; v.f = f;
  unsigned r = v.u + 0x7FFFu + ((v.u >> 16) & 1u);  // RNE
  return (unsigned short)(r >> 16);
}

#define MFMA16(a, b, c) __builtin_amdgcn_mfma_f32_16x16x32_bf16((a), (b), (c), 0, 0, 0)

// ---------------------------------------------------------------------------
// Kernel W: fp32 weights -> bf16 in MFMA A-fragment order (unchanged, verified)
// dst[((mtile*ksteps+ks)*64 + lane)*8 + j] = W[mtile*16+(lane&15)][ks*32+(lane>>4)*8+j]
// ---------------------------------------------------------------------------
__global__ void swizzle_weights(const float* __restrict__ gw1, const float* __restrict__ gw2,
                                const float* __restrict__ mw1, const float* __restrict__ mw2,
                                unsigned short* __restrict__ gw1s, unsigned short* __restrict__ gw2s,
                                unsigned short* __restrict__ mw1s, unsigned short* __restrict__ mw2s) {
  int e = blockIdx.x * 256 + threadIdx.x;   // 45056 total
  const float* src; unsigned short* dst; int ksteps, rows, K, local;
  if (e < 16384)      { src = gw1; dst = gw1s; ksteps = 2; rows = 256; K = 64;  local = e; }
  else if (e < 20480) { src = gw2; dst = gw2s; ksteps = 8; rows = 4;   K = 256; local = e - 16384; }
  else if (e < 28672) { src = mw1; dst = mw1s; ksteps = 2; rows = 128; K = 64;  local = e - 20480; }
  else                { src = mw2; dst = mw2s; ksteps = 4; rows = 128; K = 128; local = e - 28672; }
  int j = local & 7, lane = (local >> 3) & 63, tile = local >> 9;
  int ks = tile % ksteps, mtile = tile / ksteps;
  int row = mtile * 16 + (lane & 15);
  int k   = ks * 32 + ((lane >> 4) & 3) * 8 + j;
  float v = (row < rows) ? src[row * K + k] : 0.0f;   // zero-pad (gw2: 4 rows -> 16)
  dst[local] = f2bf(v);
}

// ---------------------------------------------------------------------------
// Fused kernel: per 64-node chunk (block loops over ~11 chunks, strided by NB,
// with register-prefetch of next chunk's x):
//   stage x -> bf16 LDS (double-buffered);
//   gate: h = PReLU(gw1*x^T) -> hs; gate^T = gw2pad*h^T; escore = exp(gate);
//   denom[seg][head] += escore  (tile-reduced atomics, batch sorted);
//   mlp:  h1 = relu(mw1*x^T+b1) -> h1s (aliases hs); feat^T = mw2*h1^T+b2;
//   numer[seg][fcol] += escore*feat  (accumulated into d_out, atomics);
// finalize kernel divides numer by denom.
// ---------------------------------------------------------------------------
__global__ __launch_bounds__(256, 3) void fused_kernel(
    const float* __restrict__ x, const int* __restrict__ batch,
    const unsigned short* __restrict__ gw1s, const unsigned short* __restrict__ gw2s,
    const unsigned short* __restrict__ mw1s, const unsigned short* __restrict__ mw2s,
    const float* __restrict__ prelu_a, const float* __restrict__ b1,
    const float* __restrict__ b2,
    float* __restrict__ denom, float* __restrict__ out) {
  __shared__ unsigned short xs[2][64 * 72];   // 2 x 9216 B, dbuf
  __shared__ unsigned short hs[64 * 264];     // 33792 B; h1s aliases (stride 136)
  __shared__ float score_es[256];             // escore [node64][head4]
  unsigned short* h1s = hs;

  int t = threadIdx.x;
  int wave = t >> 6, lane = t & 63;
  int quad = lane >> 4, lcol = lane & 15;
  float slope = prelu_a[0];

  float4 pf[4];
  int c = blockIdx.x;

  // prologue: issue loads for first chunk
  if (c < NC) {
#pragma unroll
    for (int i = 0; i < 4; ++i) {
      int idx = i * 1024 + t * 4;
      int gn = c * 64 + (idx >> 6), col = idx & 63;
      pf[i] = (gn < NN) ? *(const float4*)(x + (size_t)gn * 64 + col)
                        : make_float4(0.f, 0.f, 0.f, 0.f);
    }
  }

  int buf = 0;
  while (c < NC) {
    int base = c * 64;
    // ---- stage prefetched regs -> xs[buf] ----
#pragma unroll
    for (int i = 0; i < 4; ++i) {
      int idx = i * 1024 + t * 4;
      int node = idx >> 6, col = idx & 63;
      uint2 p;
      p.x = (unsigned)f2bf(pf[i].x) | ((unsigned)f2bf(pf[i].y) << 16);
      p.y = (unsigned)f2bf(pf[i].z) | ((unsigned)f2bf(pf[i].w) << 16);
      *(uint2*)(xs[buf] + node * 72 + col) = p;
    }
    // ---- issue prefetch for next chunk (stays in flight across compute) ----
    int cn = c + NB;
    if (cn < NC) {
#pragma unroll
      for (int i = 0; i < 4; ++i) {
        int idx = i * 1024 + t * 4;
        int gn = cn * 64 + (idx >> 6), col = idx & 63;
        pf[i] = (gn < NN) ? *(const float4*)(x + (size_t)gn * 64 + col)
                          : make_float4(0.f, 0.f, 0.f, 0.f);
      }
    }
    __syncthreads();   // B1: xs[buf] ready

    // ---- x^T B-fragments (shared by gate L1 and MLP L1) ----
    short8 bx[4][2];
#pragma unroll
    for (int nt = 0; nt < 4; ++nt)
#pragma unroll
      for (int ks = 0; ks < 2; ++ks)
        bx[nt][ks] = *(const short8*)(xs[buf] + (nt * 16 + lcol) * 72 + ks * 32 + quad * 8);

    // ---- gate layer1: wave w -> h wcols [w*64, w*64+64) ----
#pragma unroll
    for (int mt = 0; mt < 4; ++mt) {
      int gmt = wave * 4 + mt;
      short8 a0 = *(const short8*)(gw1s + ((size_t)(gmt * 2 + 0) * 64 + lane) * 8);
      short8 a1 = *(const short8*)(gw1s + ((size_t)(gmt * 2 + 1) * 64 + lane) * 8);
#pragma unroll
      for (int nt = 0; nt < 4; ++nt) {
        floatx4 cc = {0.f, 0.f, 0.f, 0.f};
        cc = MFMA16(a0, bx[nt][0], cc);
        cc = MFMA16(a1, bx[nt][1], cc);
        unsigned short hh[4];
#pragma unroll
        for (int r = 0; r < 4; ++r) {
          float v = cc[r];
          v = (v >= 0.f) ? v : slope * v;   // PReLU
          hh[r] = f2bf(v);
        }
        uint2 p; p.x = hh[0] | ((unsigned)hh[1] << 16); p.y = hh[2] | ((unsigned)hh[3] << 16);
        *(uint2*)(hs + (nt * 16 + lcol) * 264 + gmt * 16 + quad * 4) = p;
      }
    }
    __syncthreads();   // B2: hs ready

    // ---- gate layer2: wave w owns node tile w; K=256 ----
    floatx4 c2 = {0.f, 0.f, 0.f, 0.f};
#pragma unroll
    for (int ks = 0; ks < 8; ++ks) {
      short8 a = *(const short8*)(gw2s + ((size_t)ks * 64 + lane) * 8);
      short8 b = *(const short8*)(hs + (wave * 16 + lcol) * 264 + ks * 32 + quad * 8);
      c2 = MFMA16(a, b, c2);
    }
    int gn = base + wave * 16 + lcol;
    bool valid = gn < NN;
    float e0 = valid ? __expf(c2[0]) : 0.f;
    float e1 = valid ? __expf(c2[1]) : 0.f;
    float e2 = valid ? __expf(c2[2]) : 0.f;
    float e3 = valid ? __expf(c2[3]) : 0.f;
    if (quad == 0) {
      float4 st = make_float4(e0, e1, e2, e3);
      *(float4*)(score_es + (wave * 16 + lcol) * 4) = st;
    }
    {
      int tb = base + wave * 16;
      int segFirst = batch[tb < NN ? tb : NN - 1];
      int tl = tb + 15;
      int segLast = batch[tl < NN ? tl : NN - 1];
      if (segFirst == segLast) {   // sorted => whole 16-node tile one segment
        float s0 = e0, s1 = e1, s2 = e2, s3 = e3;
#pragma unroll
        for (int m = 1; m < 16; m <<= 1) {
          s0 += __shfl_xor(s0, m); s1 += __shfl_xor(s1, m);
          s2 += __shfl_xor(s2, m); s3 += __shfl_xor(s3, m);
        }
        if (lane == 0) {
          atomicAdd(&denom[segFirst * 4 + 0], s0);
          atomicAdd(&denom[segFirst * 4 + 1], s1);
          atomicAdd(&denom[segFirst * 4 + 2], s2);
          atomicAdd(&denom[segFirst * 4 + 3], s3);
        }
      } else if (quad == 0 && valid) {
        int seg = batch[gn];
        atomicAdd(&denom[seg * 4 + 0], e0);
        atomicAdd(&denom[seg * 4 + 1], e1);
        atomicAdd(&denom[seg * 4 + 2], e2);
        atomicAdd(&denom[seg * 4 + 3], e3);
      }
    }
    __syncthreads();   // B3: hs reads done; h1s (alias) may be written

    // ---- MLP layer1: wave w -> wcols [w*32, w*32+32) ----
#pragma unroll
    for (int mt = 0; mt < 2; ++mt) {
      int gmt = wave * 2 + mt;
      short8 a0 = *(const short8*)(mw1s + ((size_t)(gmt * 2 + 0) * 64 + lane) * 8);
      short8 a1 = *(const short8*)(mw1s + ((size_t)(gmt * 2 + 1) * 64 + lane) * 8);
      float4 bias = *(const float4*)(b1 + gmt * 16 + quad * 4);
#pragma unroll
      for (int nt = 0; nt < 4; ++nt) {
        floatx4 cc = {0.f, 0.f, 0.f, 0.f};
        cc = MFMA16(a0, bx[nt][0], cc);
        cc = MFMA16(a1, bx[nt][1], cc);
        unsigned short hh[4];
        hh[0] = f2bf(fmaxf(cc[0] + bias.x, 0.f));
        hh[1] = f2bf(fmaxf(cc[1] + bias.y, 0.f));
        hh[2] = f2bf(fmaxf(cc[2] + bias.z, 0.f));
        hh[3] = f2bf(fmaxf(cc[3] + bias.w, 0.f));
        uint2 p; p.x = hh[0] | ((unsigned)hh[1] << 16); p.y = hh[2] | ((unsigned)hh[3] << 16);
        *(uint2*)(h1s + (nt * 16 + lcol) * 136 + gmt * 16 + quad * 4) = p;
      }
    }
    __syncthreads();   // B4: h1s + score_es ready

    // ---- MLP layer2 + escore-weighted pooling; wave w owns fcols [32w,+32) ----
    short8 a2[2][4];
    float4 b2f[2];
#pragma unroll
    for (int mt = 0; mt < 2; ++mt) {
      int gmt = wave * 2 + mt;
#pragma unroll
      for (int ks = 0; ks < 4; ++ks)
        a2[mt][ks] = *(const short8*)(mw2s + ((size_t)(gmt * 4 + ks) * 64 + lane) * 8);
      b2f[mt] = *(const float4*)(b2 + gmt * 16 + quad * 4);
    }
    int lastIdx = (base + 63 < NN) ? base + 63 : NN - 1;
    int chunkUni = (batch[base] == batch[lastIdx]);
    int fcolBase0 = wave * 32 + quad * 4;

    float acc[2][4] = {{0.f,0.f,0.f,0.f},{0.f,0.f,0.f,0.f}};
#pragma unroll
    for (int nt = 0; nt < 4; ++nt) {
      short8 bh[4];
#pragma unroll
      for (int ks = 0; ks < 4; ++ks)
        bh[ks] = *(const short8*)(h1s + (nt * 16 + lcol) * 136 + ks * 32 + quad * 8);
      float sc = score_es[(nt * 16 + lcol) * 4 + wave];   // head == wave
      float contrib[2][4];
#pragma unroll
      for (int mt = 0; mt < 2; ++mt) {
        floatx4 cc = {0.f, 0.f, 0.f, 0.f};
#pragma unroll
        for (int ks = 0; ks < 4; ++ks) cc = MFMA16(a2[mt][ks], bh[ks], cc);
        contrib[mt][0] = sc * (cc[0] + b2f[mt].x);
        contrib[mt][1] = sc * (cc[1] + b2f[mt].y);
        contrib[mt][2] = sc * (cc[2] + b2f[mt].z);
        contrib[mt][3] = sc * (cc[3] + b2f[mt].w);
      }
      if (chunkUni) {
#pragma unroll
        for (int mt = 0; mt < 2; ++mt)
#pragma unroll
          for (int r = 0; r < 4; ++r) acc[mt][r] += contrib[mt][r];
      } else {
        int na = base + nt * 16, nb2 = na + 15;
        int segA = batch[na < NN ? na : NN - 1];
        int segB = batch[nb2 < NN ? nb2 : NN - 1];
        if (segA == segB) {
#pragma unroll
          for (int m = 1; m < 16; m <<= 1)
#pragma unroll
            for (int mt = 0; mt < 2; ++mt)
#pragma unroll
              for (int r = 0; r < 4; ++r)
                contrib[mt][r] += __shfl_xor(contrib[mt][r], m);
          if (lcol == 0)
#pragma unroll
            for (int mt = 0; mt < 2; ++mt)
#pragma unroll
              for (int r = 0; r < 4; ++r)
                atomicAdd(&out[segA * 128 + fcolBase0 + mt * 16 + r], contrib[mt][r]);
        } else {
          int gn2 = base + nt * 16 + lcol;
          int seg = batch[gn2 < NN ? gn2 : NN - 1];
#pragma unroll
          for (int mt = 0; mt < 2; ++mt)
#pragma unroll
            for (int r = 0; r < 4; ++r)
              atomicAdd(&out[seg * 128 + fcolBase0 + mt * 16 + r], contrib[mt][r]);
        }
      }
    }
    if (chunkUni) {
      int seg = batch[base];
#pragma unroll
      for (int m = 1; m < 16; m <<= 1)
#pragma unroll
        for (int mt = 0; mt < 2; ++mt)
#pragma unroll
          for (int r = 0; r < 4; ++r)
            acc[mt][r] += __shfl_xor(acc[mt][r], m);
      if (lcol == 0)
#pragma unroll
        for (int mt = 0; mt < 2; ++mt)
#pragma unroll
          for (int r = 0; r < 4; ++r)
            atomicAdd(&out[seg * 128 + fcolBase0 + mt * 16 + r], acc[mt][r]);
    }

    buf ^= 1;
    c = cn;
  }
}

// ---------------------------------------------------------------------------
// Finalize: out = numer / denom
// ---------------------------------------------------------------------------
__global__ void finalize_kernel(float* __restrict__ out, const float* __restrict__ denom) {
  int i = blockIdx.x * 256 + threadIdx.x;   // 131072 = 1024 segs * 128 fcols
  int seg = i >> 7, head = (i >> 5) & 3;
  out[i] = out[i] / (denom[seg * 4 + head] + 1e-16f);
}

// ---------------------------------------------------------------------------
extern "C" void kernel_launch(void* const* d_in, const int* in_sizes, int n_in,
                              void* d_out, int out_size, void* d_ws, size_t ws_size,
                              hipStream_t stream) {
  const float* x     = (const float*)d_in[0];
  const int*   batch = (const int*)d_in[1];
  // d_in[2] = num_segments (constant 1024, unused)
  const float* gw1 = (const float*)d_in[3];
  const float* pa  = (const float*)d_in[4];
  const float* gw2 = (const float*)d_in[5];
  const float* mw1 = (const float*)d_in[6];
  const float* mb1 = (const float*)d_in[7];
  const float* mw2 = (const float*)d_in[8];
  const float* mb2 = (const float*)d_in[9];
  float* out = (float*)d_out;

  char* ws = (char*)d_ws;
  float* denom = (float*)ws;                              // 4096 fp32 = 16,384 B
  unsigned short* gw1s = (unsigned short*)(ws + 16384);   // 32,768 B
  unsigned short* gw2s = (unsigned short*)(ws + 49152);   //  8,192 B
  unsigned short* mw1s = (unsigned short*)(ws + 57344);   // 16,384 B
  unsigned short* mw2s = (unsigned short*)(ws + 73728);   // 32,768 B

  hipMemsetAsync(denom, 0, 4096 * sizeof(float), stream);
  hipMemsetAsync(out, 0, (size_t)out_size * sizeof(float), stream);

  swizzle_weights<<<176, 256, 0, stream>>>(gw1, gw2, mw1, mw2, gw1s, gw2s, mw1s, mw2s);

  fused_kernel<<<NB, 256, 0, stream>>>(x, batch, gw1s, gw2s, mw1s, mw2s,
                                       pa, mb1, mb2, denom, out);

  finalize_kernel<<<512, 256, 0, stream>>>(out, denom);
}